// Round 10
// baseline (425.258 us; speedup 1.0000x reference)
//
#include <hip/hip_runtime.h>
#include <math.h>

#define S_ 2048
#define C_ 512
#define H_ 16
#define D_ 32
#define B_ 2
#define M_ (B_ * S_)
#define RSCALE 0.04419417382415922f  // 1/sqrt(512)

typedef __attribute__((ext_vector_type(8))) short bf16x8;
typedef __attribute__((ext_vector_type(4))) float f32x4;

__device__ inline unsigned short f2bf(float f) {
  unsigned u = __builtin_bit_cast(unsigned, f);
  u += 0x7FFFu + ((u >> 16) & 1u);
  return (unsigned short)(u >> 16);
}

// ---------------- convert: all fp32->bf16 conversions in ONE dispatch ----------
// y<4: inputs q/k/v/pe -> XB[y]; y==4: Wq/Wk/Wv/Wp -> W4 (1024 blocks, guarded);
// y==5: Wo -> hi/lo planes (256 blocks, guarded).
__global__ __launch_bounds__(256) void convert(
    const float* __restrict__ q, const float* __restrict__ k,
    const float* __restrict__ v, const float* __restrict__ pe,
    const float* __restrict__ Wq, const float* __restrict__ Wk,
    const float* __restrict__ Wv, const float* __restrict__ Wp,
    const float* __restrict__ Wo, short* __restrict__ XB,
    short* __restrict__ W4, short* __restrict__ WOh, short* __restrict__ WOl) {
  const int y = blockIdx.y;
  if (y < 4) {
    const float* src = y == 0 ? q : y == 1 ? k : y == 2 ? v : pe;
    const size_t i = ((size_t)blockIdx.x * 256 + threadIdx.x) * 4;
    float4 f = *(const float4*)(src + i);
    float ff[4] = {f.x, f.y, f.z, f.w};
    ushort4 hv;
    unsigned short* ph = (unsigned short*)&hv;
#pragma unroll
    for (int e = 0; e < 4; ++e) ph[e] = f2bf(ff[e]);
    *(ushort4*)(XB + (size_t)y * M_ * C_ + i) = hv;
  } else if (y == 4) {
    if (blockIdx.x >= 1024) return;
    const int z = blockIdx.x >> 8, blk = blockIdx.x & 255;
    const float* src = z == 0 ? Wq : z == 1 ? Wk : z == 2 ? Wv : Wp;
    const size_t i = ((size_t)blk * 256 + threadIdx.x) * 4;
    float4 f = *(const float4*)(src + i);
    float ff[4] = {f.x, f.y, f.z, f.w};
    ushort4 hv;
    unsigned short* ph = (unsigned short*)&hv;
#pragma unroll
    for (int e = 0; e < 4; ++e) ph[e] = f2bf(ff[e]);
    *(ushort4*)(W4 + (size_t)z * C_ * C_ + i) = hv;
  } else {
    if (blockIdx.x >= 256) return;
    const size_t i = ((size_t)blockIdx.x * 256 + threadIdx.x) * 4;
    float4 f = *(const float4*)(Wo + i);
    float ff[4] = {f.x, f.y, f.z, f.w};
    ushort4 hv, lv;
    unsigned short* ph = (unsigned short*)&hv;
    unsigned short* pl = (unsigned short*)&lv;
#pragma unroll
    for (int e = 0; e < 4; ++e) {
      unsigned u = __builtin_bit_cast(unsigned, ff[e]);
      unsigned hi = u & 0xffff0000u;
      ph[e] = (unsigned short)(hi >> 16);
      pl[e] = f2bf(ff[e] - __builtin_bit_cast(float, hi));
    }
    *(ushort4*)(WOh + i) = hv;
    *(ushort4*)(WOl + i) = lv;
  }
}

// ---------------- proj4: LDS-free plain-bf16 GEMM, 4 projections fused --------
// grid (8, 64, 4), block 128 = 2 waves. Wave w: rows [bm+32w, bm+32w+32),
// cols [bn, bn+64). No LDS, no barriers.
__global__ __launch_bounds__(128) void proj4(
    const short* __restrict__ XB, const short* __restrict__ W4,
    const float* __restrict__ bq, const float* __restrict__ bkk,
    const float* __restrict__ bvv, const float* __restrict__ ub,
    const float* __restrict__ vb, short* __restrict__ QU,
    short* __restrict__ QV, short* __restrict__ Kb, short* __restrict__ Vt,
    short* __restrict__ POS) {
  const int z = blockIdx.z;
  const short* X = XB + (size_t)z * M_ * C_;
  const short* W = W4 + (size_t)z * C_ * C_;
  const int tid = threadIdx.x;
  const int w = tid >> 6, lane = tid & 63, col = lane & 15, quad = lane >> 4;
  const int bm = blockIdx.y * 64, bn = blockIdx.x * 64;
  const f32x4 zc = {0.f, 0.f, 0.f, 0.f};
  f32x4 acc[2][4] = {{zc, zc, zc, zc}, {zc, zc, zc, zc}};
  const short* Xr0 = X + (size_t)(bm + 32 * w + col) * C_ + quad * 8;
  const short* Xr1 = Xr0 + 16 * C_;
  const short* Wr = W + (size_t)(bn + col) * C_ + quad * 8;
#pragma unroll 4
  for (int kt = 0; kt < 16; ++kt) {
    const int k = kt * 32;
    const bf16x8 a0 = *(const bf16x8*)(Xr0 + k);
    const bf16x8 a1 = *(const bf16x8*)(Xr1 + k);
#pragma unroll
    for (int j = 0; j < 4; ++j) {
      const bf16x8 b = *(const bf16x8*)(Wr + (size_t)(16 * j) * C_ + k);
      acc[0][j] = __builtin_amdgcn_mfma_f32_16x16x32_bf16(a0, b, acc[0][j], 0, 0, 0);
      acc[1][j] = __builtin_amdgcn_mfma_f32_16x16x32_bf16(a1, b, acc[1][j], 0, 0, 0);
    }
  }
  const float* b1 = z == 0 ? bq : z == 1 ? bkk : z == 2 ? bvv : nullptr;
#pragma unroll
  for (int mt = 0; mt < 2; ++mt) {
#pragma unroll
    for (int j = 0; j < 4; ++j) {
      const int gn = bn + 16 * j + col;
      const int h = gn >> 5, d0 = gn & 31;
#pragma unroll
      for (int r = 0; r < 4; ++r) {
        const int gm = bm + 32 * w + 16 * mt + quad * 4 + r;
        const int bb = gm >> 11, s = gm & (S_ - 1);
        const float a = acc[mt][j][r] + (b1 ? b1[gn] : 0.0f);
        if (z == 0) {
          const size_t base = ((size_t)(bb * H_ + h) * S_ + s) * D_ + d0;
          QU[base] = (short)f2bf(a + ub[gn]);
          QV[base] = (short)f2bf(a + vb[gn]);
        } else if (z == 1) {
          Kb[((size_t)(bb * H_ + h) * S_ + s) * D_ + d0] = (short)f2bf(a);
        } else if (z == 2) {
          Vt[((size_t)(bb * H_ + h) * D_ + d0) * S_ + s] = (short)f2bf(a);
        } else {
          POS[((size_t)(bb * H_ + h) * S_ + s) * D_ + d0] = (short)f2bf(a);
        }
      }
    }
  }
}

// ---------------- out-projection: LDS-free hi/lo bf16 GEMM (fp32 accuracy) ----
// grid (8, 64), block 128 = 2 waves.
__global__ __launch_bounds__(128) void gemm_out(
    const short* __restrict__ CTXh, const short* __restrict__ CTXl,
    const short* __restrict__ WOh, const short* __restrict__ WOl,
    const float* __restrict__ bo, float* __restrict__ out) {
  const int tid = threadIdx.x;
  const int w = tid >> 6, lane = tid & 63, col = lane & 15, quad = lane >> 4;
  const int bm = blockIdx.y * 64, bn = blockIdx.x * 64;
  const f32x4 zc = {0.f, 0.f, 0.f, 0.f};
  f32x4 acc[2][4] = {{zc, zc, zc, zc}, {zc, zc, zc, zc}};
  const size_t a0off = (size_t)(bm + 32 * w + col) * C_ + quad * 8;
  const size_t a1off = a0off + (size_t)16 * C_;
  const size_t boff = (size_t)(bn + col) * C_ + quad * 8;
#pragma unroll 2
  for (int kt = 0; kt < 16; ++kt) {
    const int k = kt * 32;
    const bf16x8 ah0 = *(const bf16x8*)(CTXh + a0off + k);
    const bf16x8 al0 = *(const bf16x8*)(CTXl + a0off + k);
    const bf16x8 ah1 = *(const bf16x8*)(CTXh + a1off + k);
    const bf16x8 al1 = *(const bf16x8*)(CTXl + a1off + k);
#pragma unroll
    for (int j = 0; j < 4; ++j) {
      const size_t bo_ = boff + (size_t)(16 * j) * C_ + k;
      const bf16x8 bh = *(const bf16x8*)(WOh + bo_);
      const bf16x8 bl = *(const bf16x8*)(WOl + bo_);
      acc[0][j] = __builtin_amdgcn_mfma_f32_16x16x32_bf16(ah0, bh, acc[0][j], 0, 0, 0);
      acc[0][j] = __builtin_amdgcn_mfma_f32_16x16x32_bf16(ah0, bl, acc[0][j], 0, 0, 0);
      acc[0][j] = __builtin_amdgcn_mfma_f32_16x16x32_bf16(al0, bh, acc[0][j], 0, 0, 0);
      acc[1][j] = __builtin_amdgcn_mfma_f32_16x16x32_bf16(ah1, bh, acc[1][j], 0, 0, 0);
      acc[1][j] = __builtin_amdgcn_mfma_f32_16x16x32_bf16(ah1, bl, acc[1][j], 0, 0, 0);
      acc[1][j] = __builtin_amdgcn_mfma_f32_16x16x32_bf16(al1, bh, acc[1][j], 0, 0, 0);
    }
  }
#pragma unroll
  for (int mt = 0; mt < 2; ++mt) {
#pragma unroll
    for (int j = 0; j < 4; ++j) {
      const int gn = bn + 16 * j + col;
#pragma unroll
      for (int r = 0; r < 4; ++r) {
        const int gm = bm + 32 * w + 16 * mt + quad * 4 + r;
        out[(size_t)gm * C_ + gn] = acc[mt][j][r] + bo[gn];
      }
    }
  }
}

// ---------------- Fused relative attention: merged-band, 2 barriers/chunk -----
// Loads stay INLINE at their R4 positions (K at chunk top, Ph inside band
// sections, V in PV phase). Bands write disjoint predicated columns of PB:
// bandA cc <= 63-dnm (== t <= S-1 == u <= 0), bandB cc >= 65-dnm (== t >= 0
// == u >= 2); cc == 64-dnm is u==1, never written, never read. dnm is a
// multiple of 64, so the only chunk leaving a readable-looking hole (dnm=64,
// cc=0) is exactly u==1. OOB Ph reads land in adjacent ws buffers (allocated)
// and are discarded by the write predicate.
__global__ __launch_bounds__(256, 4) void attn_mfma(
    const short* __restrict__ QU, const short* __restrict__ QV,
    const short* __restrict__ Kb, const short* __restrict__ Vt,
    const short* __restrict__ POSb, short* __restrict__ CTXh,
    short* __restrict__ CTXl) {
  __shared__ float PB[64 * 128];   // 32 KB band buffer (swizzled cols)
  __shared__ short Pl[64 * 64];    // 8 KB P tile bf16 (swizzled cols)
  const int tid = threadIdx.x;
  const int w = tid >> 6;
  const int lane = tid & 63;
  const int col = lane & 15;
  const int quad = lane >> 4;
  const int m0 = blockIdx.x * 64;
  const int bh = blockIdx.y;
  const int b = bh >> 4, h = bh & 15;

  const short* QUh = QU + (size_t)bh * S_ * D_;
  const short* QVh = QV + (size_t)bh * S_ * D_;
  const short* Kh = Kb + (size_t)bh * S_ * D_;
  const short* Vh = Vt + (size_t)bh * D_ * S_;
  const short* Ph = POSb + (size_t)bh * S_ * D_;

  const int arow = m0 + 16 * w + col;
  const bf16x8 aQU = *(const bf16x8*)(QUh + (size_t)arow * D_ + quad * 8);
  const bf16x8 aQVA = *(const bf16x8*)(QVh + (size_t)arow * D_ + quad * 8);
  const bf16x8 aQVB = *(const bf16x8*)(QVh + (size_t)(arow + 1) * D_ + quad * 8);

  const f32x4 zc = {0.f, 0.f, 0.f, 0.f};
  f32x4 ctxa0 = zc, ctxa1 = zc;
  float lpart[4] = {0.f, 0.f, 0.f, 0.f};
  const int mi0 = 16 * w + 4 * quad;
  const int swz0 = ((mi0 & 4) << 2) ^ ((mi0 & 3) << 3);  // swz(mi0+r) = swz0^(r<<3)

  for (int ch = 0; ch < 32; ++ch) {
    const int n0 = ch * 64;
    const int dnm = n0 - m0;
    // ---- content scores (K loads inline) ----
    f32x4 sc[4];
#pragma unroll
    for (int j = 0; j < 4; ++j) {
      bf16x8 bk = *(const bf16x8*)(Kh + (size_t)(n0 + 16 * j + col) * D_ + quad * 8);
      sc[j] = __builtin_amdgcn_mfma_f32_16x16x32_bf16(aQU, bk, zc, 0, 0, 0);
    }
    // ---- band A (u<=0): predicated disjoint PB writes ----
    if (dnm <= 63) {
      const int tA0 = S_ - 64 + dnm;
#pragma unroll
      for (int j = 0; j < 8; ++j) {
        const int t = tA0 + 16 * j + col;
        bf16x8 bp = *(const bf16x8*)(Ph + (long)t * D_ + quad * 8);
        f32x4 c = __builtin_amdgcn_mfma_f32_16x16x32_bf16(aQVA, bp, zc, 0, 0, 0);
        const int cc = 16 * j + col;
        if (cc <= 63 - dnm) {
#pragma unroll
          for (int r = 0; r < 4; ++r)
            PB[(mi0 + r) * 128 + (cc ^ (swz0 ^ (r << 3)))] = c[r];
        }
      }
    }
    // ---- band B (u>=2): predicated disjoint PB writes ----
    if (dnm >= -61) {
      const int tB0 = dnm - 65;
#pragma unroll
      for (int j = 0; j < 8; ++j) {
        const int t = tB0 + 16 * j + col;
        bf16x8 bp = *(const bf16x8*)(Ph + (long)t * D_ + quad * 8);
        f32x4 c = __builtin_amdgcn_mfma_f32_16x16x32_bf16(aQVB, bp, zc, 0, 0, 0);
        const int cc = 16 * j + col;
        if (cc >= 65 - dnm) {
#pragma unroll
          for (int r = 0; r < 4; ++r)
            PB[(mi0 + r) * 128 + (cc ^ (swz0 ^ (r << 3)))] = c[r];
        }
      }
    }
    __syncthreads();  // B1: PB ready; prev chunk's PV Pl-reads also complete
    // ---- gather + exp + Pl write (fused) ----
#pragma unroll
    for (int j = 0; j < 4; ++j)
#pragma unroll
      for (int r = 0; r < 4; ++r) {
        const int mi = mi0 + r;
        const int nj = 16 * j + col;
        const int u = dnm + nj - mi;
        float bandv = 0.0f;
        if (u <= 0 || u >= 2)
          bandv = PB[mi * 128 + ((nj - mi + 63) ^ (swz0 ^ (r << 3)))];
        const float p = __expf((sc[j][r] + bandv) * RSCALE);
        lpart[r] += p;
        Pl[mi * 64 + ((16 * j + col) ^ ((mi & 7) << 3))] = (short)f2bf(p);
      }
    __syncthreads();  // B2: Pl ready
    // ---- PV (V loads inline) ----
    const int prow = 16 * w + col;
    const int psw = (prow & 7) << 3;
#pragma unroll
    for (int k0 = 0; k0 < 2; ++k0) {
      const bf16x8 ap = *(const bf16x8*)(&Pl[prow * 64 + ((k0 * 32 + quad * 8) ^ psw)]);
      bf16x8 bv0 = *(const bf16x8*)(Vh + (size_t)col * S_ + n0 + k0 * 32 + quad * 8);
      ctxa0 = __builtin_amdgcn_mfma_f32_16x16x32_bf16(ap, bv0, ctxa0, 0, 0, 0);
      bf16x8 bv1 = *(const bf16x8*)(Vh + (size_t)(16 + col) * S_ + n0 + k0 * 32 + quad * 8);
      ctxa1 = __builtin_amdgcn_mfma_f32_16x16x32_bf16(ap, bv1, ctxa1, 0, 0, 0);
    }
  }
#pragma unroll
  for (int r = 0; r < 4; ++r) {
    float s = lpart[r];
    s += __shfl_xor(s, 1);
    s += __shfl_xor(s, 2);
    s += __shfl_xor(s, 4);
    s += __shfl_xor(s, 8);
    lpart[r] = 1.0f / s;
  }
  const int mrow = m0 + mi0;
#pragma unroll
  for (int r = 0; r < 4; ++r) {
    const size_t obase = ((size_t)(b * S_ + mrow + r)) * C_ + h * D_;
    const float v0 = ctxa0[r] * lpart[r];
    const float v1 = ctxa1[r] * lpart[r];
    const unsigned u0 = __builtin_bit_cast(unsigned, v0) & 0xffff0000u;
    const unsigned u1 = __builtin_bit_cast(unsigned, v1) & 0xffff0000u;
    CTXh[obase + col] = (short)(u0 >> 16);
    CTXl[obase + col] = (short)f2bf(v0 - __builtin_bit_cast(float, u0));
    CTXh[obase + 16 + col] = (short)(u1 >> 16);
    CTXl[obase + 16 + col] = (short)f2bf(v1 - __builtin_bit_cast(float, u1));
  }
}

extern "C" void kernel_launch(void* const* d_in, const int* in_sizes, int n_in,
                              void* d_out, int out_size, void* d_ws, size_t ws_size,
                              hipStream_t stream) {
  (void)in_sizes; (void)n_in; (void)out_size; (void)ws_size;
  const float* q = (const float*)d_in[0];
  const float* k = (const float*)d_in[1];
  const float* v = (const float*)d_in[2];
  const float* pe = (const float*)d_in[3];
  const float* Wq = (const float*)d_in[4];
  const float* bq = (const float*)d_in[5];
  const float* Wk = (const float*)d_in[6];
  const float* bk = (const float*)d_in[7];
  const float* Wv = (const float*)d_in[8];
  const float* bv = (const float*)d_in[9];
  const float* Wp = (const float*)d_in[10];
  const float* ub = (const float*)d_in[11];
  const float* vb = (const float*)d_in[12];
  const float* Wo = (const float*)d_in[13];
  const float* bo = (const float*)d_in[14];
  float* out = (float*)d_out;

  const size_t MC = (size_t)M_ * C_;
  const size_t WC = (size_t)C_ * C_;
  short* XB = (short*)d_ws;            // [4][M][C] plain bf16
  short* W4 = XB + 4 * MC;             // [4][C][C] plain bf16
  short* WOh = W4 + 4 * WC;            // [C][C] hi
  short* WOl = WOh + WC;               // [C][C] lo
  short* QUb = WOl + WC;
  short* QVb = QUb + MC;
  short* Kbb = QVb + MC;
  short* Vtb = Kbb + MC;
  short* POSB = Vtb + MC;
  short* CTXh = POSB + MC;
  short* CTXl = CTXh + MC;

  convert<<<dim3(2048, 6), 256, 0, stream>>>(q, k, v, pe, Wq, Wk, Wv, Wp, Wo,
                                             XB, W4, WOh, WOl);
  proj4<<<dim3(8, 64, 4), 128, 0, stream>>>(XB, W4, bq, bk, bv, ub, vb,
                                            QUb, QVb, Kbb, Vtb, POSB);
  attn_mfma<<<dim3(S_ / 64, B_ * H_), 256, 0, stream>>>(QUb, QVb, Kbb, Vtb, POSB,
                                                        CTXh, CTXl);
  gemm_out<<<dim3(8, 64), 128, 0, stream>>>(CTXh, CTXl, WOh, WOl, bo, out);
}

// Round 11
// 369.413 us; speedup vs baseline: 1.1512x; 1.1512x over previous
//
#include <hip/hip_runtime.h>
#include <math.h>

#define S_ 2048
#define C_ 512
#define H_ 16
#define D_ 32
#define B_ 2
#define M_ (B_ * S_)
#define RSCALE 0.04419417382415922f  // 1/sqrt(512)

typedef __attribute__((ext_vector_type(8))) short bf16x8;
typedef __attribute__((ext_vector_type(4))) float f32x4;

__device__ inline unsigned short f2bf(float f) {
  unsigned u = __builtin_bit_cast(unsigned, f);
  u += 0x7FFFu + ((u >> 16) & 1u);
  return (unsigned short)(u >> 16);
}

// ---------------- convert: all fp32->bf16 conversions in ONE dispatch ----------
__global__ __launch_bounds__(256) void convert(
    const float* __restrict__ q, const float* __restrict__ k,
    const float* __restrict__ v, const float* __restrict__ pe,
    const float* __restrict__ Wq, const float* __restrict__ Wk,
    const float* __restrict__ Wv, const float* __restrict__ Wp,
    const float* __restrict__ Wo, short* __restrict__ XB,
    short* __restrict__ W4, short* __restrict__ WOh, short* __restrict__ WOl) {
  const int y = blockIdx.y;
  if (y < 4) {
    const float* src = y == 0 ? q : y == 1 ? k : y == 2 ? v : pe;
    const size_t i = ((size_t)blockIdx.x * 256 + threadIdx.x) * 4;
    float4 f = *(const float4*)(src + i);
    float ff[4] = {f.x, f.y, f.z, f.w};
    ushort4 hv;
    unsigned short* ph = (unsigned short*)&hv;
#pragma unroll
    for (int e = 0; e < 4; ++e) ph[e] = f2bf(ff[e]);
    *(ushort4*)(XB + (size_t)y * M_ * C_ + i) = hv;
  } else if (y == 4) {
    if (blockIdx.x >= 1024) return;
    const int z = blockIdx.x >> 8, blk = blockIdx.x & 255;
    const float* src = z == 0 ? Wq : z == 1 ? Wk : z == 2 ? Wv : Wp;
    const size_t i = ((size_t)blk * 256 + threadIdx.x) * 4;
    float4 f = *(const float4*)(src + i);
    float ff[4] = {f.x, f.y, f.z, f.w};
    ushort4 hv;
    unsigned short* ph = (unsigned short*)&hv;
#pragma unroll
    for (int e = 0; e < 4; ++e) ph[e] = f2bf(ff[e]);
    *(ushort4*)(W4 + (size_t)z * C_ * C_ + i) = hv;
  } else {
    if (blockIdx.x >= 256) return;
    const size_t i = ((size_t)blockIdx.x * 256 + threadIdx.x) * 4;
    float4 f = *(const float4*)(Wo + i);
    float ff[4] = {f.x, f.y, f.z, f.w};
    ushort4 hv, lv;
    unsigned short* ph = (unsigned short*)&hv;
    unsigned short* pl = (unsigned short*)&lv;
#pragma unroll
    for (int e = 0; e < 4; ++e) {
      unsigned u = __builtin_bit_cast(unsigned, ff[e]);
      unsigned hi = u & 0xffff0000u;
      ph[e] = (unsigned short)(hi >> 16);
      pl[e] = f2bf(ff[e] - __builtin_bit_cast(float, hi));
    }
    *(ushort4*)(WOh + i) = hv;
    *(ushort4*)(WOl + i) = lv;
  }
}

// ---------------- proj4: LDS-free plain-bf16 GEMM, 4 projections fused --------
__global__ __launch_bounds__(128) void proj4(
    const short* __restrict__ XB, const short* __restrict__ W4,
    const float* __restrict__ bq, const float* __restrict__ bkk,
    const float* __restrict__ bvv, const float* __restrict__ ub,
    const float* __restrict__ vb, short* __restrict__ QU,
    short* __restrict__ QV, short* __restrict__ Kb, short* __restrict__ Vt,
    short* __restrict__ POS) {
  const int z = blockIdx.z;
  const short* X = XB + (size_t)z * M_ * C_;
  const short* W = W4 + (size_t)z * C_ * C_;
  const int tid = threadIdx.x;
  const int w = tid >> 6, lane = tid & 63, col = lane & 15, quad = lane >> 4;
  const int bm = blockIdx.y * 64, bn = blockIdx.x * 64;
  const f32x4 zc = {0.f, 0.f, 0.f, 0.f};
  f32x4 acc[2][4] = {{zc, zc, zc, zc}, {zc, zc, zc, zc}};
  const short* Xr0 = X + (size_t)(bm + 32 * w + col) * C_ + quad * 8;
  const short* Xr1 = Xr0 + 16 * C_;
  const short* Wr = W + (size_t)(bn + col) * C_ + quad * 8;
#pragma unroll 4
  for (int kt = 0; kt < 16; ++kt) {
    const int k = kt * 32;
    const bf16x8 a0 = *(const bf16x8*)(Xr0 + k);
    const bf16x8 a1 = *(const bf16x8*)(Xr1 + k);
#pragma unroll
    for (int j = 0; j < 4; ++j) {
      const bf16x8 b = *(const bf16x8*)(Wr + (size_t)(16 * j) * C_ + k);
      acc[0][j] = __builtin_amdgcn_mfma_f32_16x16x32_bf16(a0, b, acc[0][j], 0, 0, 0);
      acc[1][j] = __builtin_amdgcn_mfma_f32_16x16x32_bf16(a1, b, acc[1][j], 0, 0, 0);
    }
  }
  const float* b1 = z == 0 ? bq : z == 1 ? bkk : z == 2 ? bvv : nullptr;
#pragma unroll
  for (int mt = 0; mt < 2; ++mt) {
#pragma unroll
    for (int j = 0; j < 4; ++j) {
      const int gn = bn + 16 * j + col;
      const int h = gn >> 5, d0 = gn & 31;
#pragma unroll
      for (int r = 0; r < 4; ++r) {
        const int gm = bm + 32 * w + 16 * mt + quad * 4 + r;
        const int bb = gm >> 11, s = gm & (S_ - 1);
        const float a = acc[mt][j][r] + (b1 ? b1[gn] : 0.0f);
        if (z == 0) {
          const size_t base = ((size_t)(bb * H_ + h) * S_ + s) * D_ + d0;
          QU[base] = (short)f2bf(a + ub[gn]);
          QV[base] = (short)f2bf(a + vb[gn]);
        } else if (z == 1) {
          Kb[((size_t)(bb * H_ + h) * S_ + s) * D_ + d0] = (short)f2bf(a);
        } else if (z == 2) {
          Vt[((size_t)(bb * H_ + h) * D_ + d0) * S_ + s] = (short)f2bf(a);
        } else {
          POS[((size_t)(bb * H_ + h) * S_ + s) * D_ + d0] = (short)f2bf(a);
        }
      }
    }
  }
}

// ---------------- out-projection: LDS-free hi/lo bf16 GEMM (fp32 accuracy) ----
__global__ __launch_bounds__(128) void gemm_out(
    const short* __restrict__ CTXh, const short* __restrict__ CTXl,
    const short* __restrict__ WOh, const short* __restrict__ WOl,
    const float* __restrict__ bo, float* __restrict__ out) {
  const int tid = threadIdx.x;
  const int w = tid >> 6, lane = tid & 63, col = lane & 15, quad = lane >> 4;
  const int bm = blockIdx.y * 64, bn = blockIdx.x * 64;
  const f32x4 zc = {0.f, 0.f, 0.f, 0.f};
  f32x4 acc[2][4] = {{zc, zc, zc, zc}, {zc, zc, zc, zc}};
  const size_t a0off = (size_t)(bm + 32 * w + col) * C_ + quad * 8;
  const size_t a1off = a0off + (size_t)16 * C_;
  const size_t boff = (size_t)(bn + col) * C_ + quad * 8;
#pragma unroll 2
  for (int kt = 0; kt < 16; ++kt) {
    const int k = kt * 32;
    const bf16x8 ah0 = *(const bf16x8*)(CTXh + a0off + k);
    const bf16x8 al0 = *(const bf16x8*)(CTXl + a0off + k);
    const bf16x8 ah1 = *(const bf16x8*)(CTXh + a1off + k);
    const bf16x8 al1 = *(const bf16x8*)(CTXl + a1off + k);
#pragma unroll
    for (int j = 0; j < 4; ++j) {
      const size_t bo_ = boff + (size_t)(16 * j) * C_ + k;
      const bf16x8 bh = *(const bf16x8*)(WOh + bo_);
      const bf16x8 bl = *(const bf16x8*)(WOl + bo_);
      acc[0][j] = __builtin_amdgcn_mfma_f32_16x16x32_bf16(ah0, bh, acc[0][j], 0, 0, 0);
      acc[0][j] = __builtin_amdgcn_mfma_f32_16x16x32_bf16(ah0, bl, acc[0][j], 0, 0, 0);
      acc[0][j] = __builtin_amdgcn_mfma_f32_16x16x32_bf16(al0, bh, acc[0][j], 0, 0, 0);
      acc[1][j] = __builtin_amdgcn_mfma_f32_16x16x32_bf16(ah1, bh, acc[1][j], 0, 0, 0);
      acc[1][j] = __builtin_amdgcn_mfma_f32_16x16x32_bf16(ah1, bl, acc[1][j], 0, 0, 0);
      acc[1][j] = __builtin_amdgcn_mfma_f32_16x16x32_bf16(al1, bh, acc[1][j], 0, 0, 0);
    }
  }
#pragma unroll
  for (int mt = 0; mt < 2; ++mt) {
#pragma unroll
    for (int j = 0; j < 4; ++j) {
      const int gn = bn + 16 * j + col;
#pragma unroll
      for (int r = 0; r < 4; ++r) {
        const int gm = bm + 32 * w + 16 * mt + quad * 4 + r;
        out[(size_t)gm * C_ + gn] = acc[mt][j][r] + bo[gn];
      }
    }
  }
}

// ---------------- Fused relative attention: R4 body, BARRIER-FREE -------------
// All LDS rows (PB, Pl) are wave-private: wave w writes/reads only rows
// [16w, 16w+16). Same-wave LDS write->read ordering is guaranteed by
// compiler-inserted s_waitcnt lgkmcnt — the 5 __syncthreads of the R4 body
// ordered nothing cross-wave and are deleted. Everything else is identical
// to the frozen R4/R7 body (load order, predicates, PB/Pl swizzles).
__global__ __launch_bounds__(256, 4) void attn_mfma(
    const short* __restrict__ QU, const short* __restrict__ QV,
    const short* __restrict__ Kb, const short* __restrict__ Vt,
    const short* __restrict__ POSb, short* __restrict__ CTXh,
    short* __restrict__ CTXl) {
  __shared__ float PB[64 * 128];   // 32 KB band buffer (swizzled cols)
  __shared__ short Pl[64 * 64];    // 8 KB P tile bf16 (swizzled cols)
  const int tid = threadIdx.x;
  const int w = tid >> 6;
  const int lane = tid & 63;
  const int col = lane & 15;
  const int quad = lane >> 4;
  const int m0 = blockIdx.x * 64;
  const int bh = blockIdx.y;
  const int b = bh >> 4, h = bh & 15;

  const short* QUh = QU + (size_t)bh * S_ * D_;
  const short* QVh = QV + (size_t)bh * S_ * D_;
  const short* Kh = Kb + (size_t)bh * S_ * D_;
  const short* Vh = Vt + (size_t)bh * D_ * S_;
  const short* Ph = POSb + (size_t)bh * S_ * D_;

  const int arow = m0 + 16 * w + col;
  const bf16x8 aQU = *(const bf16x8*)(QUh + (size_t)arow * D_ + quad * 8);
  const bf16x8 aQVA = *(const bf16x8*)(QVh + (size_t)arow * D_ + quad * 8);
  const bf16x8 aQVB = *(const bf16x8*)(QVh + (size_t)(arow + 1) * D_ + quad * 8);

  const f32x4 zc = {0.f, 0.f, 0.f, 0.f};
  const bf16x8 zb = {0, 0, 0, 0, 0, 0, 0, 0};
  f32x4 ctxa0 = zc, ctxa1 = zc;
  float lpart[4] = {0.f, 0.f, 0.f, 0.f};
  const int mi0 = 16 * w + 4 * quad;

  for (int ch = 0; ch < 32; ++ch) {
    const int n0 = ch * 64;
    const int dnm = n0 - m0;
    f32x4 sc[4];
#pragma unroll
    for (int j = 0; j < 4; ++j) {
      bf16x8 bk = *(const bf16x8*)(Kh + (size_t)(n0 + 16 * j + col) * D_ + quad * 8);
      sc[j] = __builtin_amdgcn_mfma_f32_16x16x32_bf16(aQU, bk, zc, 0, 0, 0);
    }
    if (dnm <= 63) {
      const int tA0 = S_ - 64 + dnm;
#pragma unroll
      for (int j = 0; j < 8; ++j) {
        const int t = tA0 + 16 * j + col;
        bf16x8 bp = *(const bf16x8*)(Ph + (long)t * D_ + quad * 8);
        if (t >= S_) bp = zb;
        f32x4 c = __builtin_amdgcn_mfma_f32_16x16x32_bf16(aQVA, bp, zc, 0, 0, 0);
#pragma unroll
        for (int r = 0; r < 4; ++r) {
          const int mi = mi0 + r;
          const int cc = (16 * j + col) ^ (((mi & 4) << 2) ^ ((mi & 3) << 3));
          PB[mi * 128 + cc] = c[r];
        }
      }
#pragma unroll
      for (int j = 0; j < 4; ++j)
#pragma unroll
        for (int r = 0; r < 4; ++r) {
          const int mi = mi0 + r;
          const int nj = 16 * j + col;
          if (dnm + nj - mi <= 0) {
            const int idx = (nj - mi + 63) ^ (((mi & 4) << 2) ^ ((mi & 3) << 3));
            sc[j][r] += PB[mi * 128 + idx];
          }
        }
    }
    if (dnm >= -61) {
      const int tB0 = dnm - 65;
#pragma unroll
      for (int j = 0; j < 8; ++j) {
        const int t = tB0 + 16 * j + col;
        bf16x8 bp = *(const bf16x8*)(Ph + (long)t * D_ + quad * 8);
        if (t < 0) bp = zb;
        f32x4 c = __builtin_amdgcn_mfma_f32_16x16x32_bf16(aQVB, bp, zc, 0, 0, 0);
#pragma unroll
        for (int r = 0; r < 4; ++r) {
          const int mi = mi0 + r;
          const int cc = (16 * j + col) ^ (((mi & 4) << 2) ^ ((mi & 3) << 3));
          PB[mi * 128 + cc] = c[r];
        }
      }
#pragma unroll
      for (int j = 0; j < 4; ++j)
#pragma unroll
        for (int r = 0; r < 4; ++r) {
          const int mi = mi0 + r;
          const int nj = 16 * j + col;
          if (dnm + nj - mi >= 2) {
            const int idx = (nj - mi + 63) ^ (((mi & 4) << 2) ^ ((mi & 3) << 3));
            sc[j][r] += PB[mi * 128 + idx];
          }
        }
    }
#pragma unroll
    for (int j = 0; j < 4; ++j)
#pragma unroll
      for (int r = 0; r < 4; ++r) {
        const float p = __expf(sc[j][r] * RSCALE);
        lpart[r] += p;
        const int mi = mi0 + r;
        const int cc = (16 * j + col) ^ ((mi & 7) << 3);
        Pl[mi * 64 + cc] = (short)f2bf(p);
      }
    const int prow = 16 * w + col;
    const int psw = (prow & 7) << 3;
#pragma unroll
    for (int k0 = 0; k0 < 2; ++k0) {
      const bf16x8 ap = *(const bf16x8*)(&Pl[prow * 64 + ((k0 * 32 + quad * 8) ^ psw)]);
      bf16x8 bv0 = *(const bf16x8*)(Vh + (size_t)col * S_ + n0 + k0 * 32 + quad * 8);
      ctxa0 = __builtin_amdgcn_mfma_f32_16x16x32_bf16(ap, bv0, ctxa0, 0, 0, 0);
      bf16x8 bv1 = *(const bf16x8*)(Vh + (size_t)(16 + col) * S_ + n0 + k0 * 32 + quad * 8);
      ctxa1 = __builtin_amdgcn_mfma_f32_16x16x32_bf16(ap, bv1, ctxa1, 0, 0, 0);
    }
  }
#pragma unroll
  for (int r = 0; r < 4; ++r) {
    float s = lpart[r];
    s += __shfl_xor(s, 1);
    s += __shfl_xor(s, 2);
    s += __shfl_xor(s, 4);
    s += __shfl_xor(s, 8);
    lpart[r] = 1.0f / s;
  }
  const int mrow = m0 + mi0;
#pragma unroll
  for (int r = 0; r < 4; ++r) {
    const size_t obase = ((size_t)(b * S_ + mrow + r)) * C_ + h * D_;
    const float v0 = ctxa0[r] * lpart[r];
    const float v1 = ctxa1[r] * lpart[r];
    const unsigned u0 = __builtin_bit_cast(unsigned, v0) & 0xffff0000u;
    const unsigned u1 = __builtin_bit_cast(unsigned, v1) & 0xffff0000u;
    CTXh[obase + col] = (short)(u0 >> 16);
    CTXl[obase + col] = (short)f2bf(v0 - __builtin_bit_cast(float, u0));
    CTXh[obase + 16 + col] = (short)(u1 >> 16);
    CTXl[obase + 16 + col] = (short)f2bf(v1 - __builtin_bit_cast(float, u1));
  }
}

extern "C" void kernel_launch(void* const* d_in, const int* in_sizes, int n_in,
                              void* d_out, int out_size, void* d_ws, size_t ws_size,
                              hipStream_t stream) {
  (void)in_sizes; (void)n_in; (void)out_size; (void)ws_size;
  const float* q = (const float*)d_in[0];
  const float* k = (const float*)d_in[1];
  const float* v = (const float*)d_in[2];
  const float* pe = (const float*)d_in[3];
  const float* Wq = (const float*)d_in[4];
  const float* bq = (const float*)d_in[5];
  const float* Wk = (const float*)d_in[6];
  const float* bk = (const float*)d_in[7];
  const float* Wv = (const float*)d_in[8];
  const float* bv = (const float*)d_in[9];
  const float* Wp = (const float*)d_in[10];
  const float* ub = (const float*)d_in[11];
  const float* vb = (const float*)d_in[12];
  const float* Wo = (const float*)d_in[13];
  const float* bo = (const float*)d_in[14];
  float* out = (float*)d_out;

  const size_t MC = (size_t)M_ * C_;
  const size_t WC = (size_t)C_ * C_;
  short* XB = (short*)d_ws;            // [4][M][C] plain bf16
  short* W4 = XB + 4 * MC;             // [4][C][C] plain bf16
  short* WOh = W4 + 4 * WC;            // [C][C] hi
  short* WOl = WOh + WC;               // [C][C] lo
  short* QUb = WOl + WC;
  short* QVb = QUb + MC;
  short* Kbb = QVb + MC;
  short* Vtb = Kbb + MC;
  short* POSB = Vtb + MC;
  short* CTXh = POSB + MC;
  short* CTXl = CTXh + MC;

  convert<<<dim3(2048, 6), 256, 0, stream>>>(q, k, v, pe, Wq, Wk, Wv, Wp, Wo,
                                             XB, W4, WOh, WOl);
  proj4<<<dim3(8, 64, 4), 128, 0, stream>>>(XB, W4, bq, bk, bv, ub, vb,
                                            QUb, QVb, Kbb, Vtb, POSB);
  attn_mfma<<<dim3(S_ / 64, B_ * H_), 256, 0, stream>>>(QUb, QVb, Kbb, Vtb, POSB,
                                                        CTXh, CTXl);
  gemm_out<<<dim3(8, 64), 128, 0, stream>>>(CTXh, CTXl, WOh, WOl, bo, out);
}